// Round 4
// baseline (140.231 us; speedup 1.0000x reference)
//
#include <hip/hip_runtime.h>
#include <hip/hip_bf16.h>
#include <math.h>

// Problem constants
#define Bdim 2
#define Tdim 512
#define Cdim 256
#define Hdim 8
#define Edim 32
#define NTYPES 16
#define TI 8       // i-tile size
#define JT 128     // j-tile size

// ---------------------------------------------------------------------------
// Kernel 1: fused edge-tables + qkv GEMM.
// blocks 0..383: qkv GEMM (M=1024,K=256,N=768), 32x64 tile, scatter (B,H,T,E)
// blocks 384..399: ekt/evt = emb[t] @ w_edge_{k,v}
// ---------------------------------------------------------------------------
__global__ __launch_bounds__(256) void pre_kernel(
    const float* __restrict__ A, const float* __restrict__ Bw,
    const float* __restrict__ emb, const float* __restrict__ wk,
    const float* __restrict__ wv,
    float* __restrict__ qT, float* __restrict__ kT, float* __restrict__ vT,
    float* __restrict__ ekt, float* __restrict__ evt)
{
    __shared__ float smem[16 * 34 + 16 * 64];
    int tid = threadIdx.x;

    if (blockIdx.x >= 384) {
        // ---- edge tables ----
        int t = blockIdx.x - 384;
        float* se = smem;
        se[tid] = emb[t * Cdim + tid];
        __syncthreads();
        float a = 0.f, b = 0.f;
        for (int k = 0; k < Cdim; ++k) {
            float ev = se[k];
            a = fmaf(ev, wk[k * Cdim + tid], a);
            b = fmaf(ev, wv[k * Cdim + tid], b);
        }
        ekt[t * Cdim + tid] = a;
        evt[t * Cdim + tid] = b;
        return;
    }

    // ---- qkv GEMM, 32x64 tile, 256 threads, 2x4 per thread ----
    const int N = 3 * Cdim;
    const int K = Cdim;
    float (*As)[34] = (float(*)[34])smem;              // k-major
    float (*Bs)[64] = (float(*)[64])(smem + 16 * 34);
    int m0 = (blockIdx.x / 12) * 32;
    int n0 = (blockIdx.x % 12) * 64;
    int tr = tid >> 4, tc = tid & 15;                  // 16 row-pairs x 16 col-quads
    float acc[2][4] = {};
    int bkr = tid >> 4, bcq = (tid & 15) * 4;

    for (int k0 = 0; k0 < K; k0 += 16) {
        if (tid < 128) {
            int r = tid >> 2, kq = (tid & 3) * 4;
            float4 av = *(const float4*)(A + (size_t)(m0 + r) * K + k0 + kq);
            As[kq + 0][r] = av.x;
            As[kq + 1][r] = av.y;
            As[kq + 2][r] = av.z;
            As[kq + 3][r] = av.w;
        }
        float4 bv = *(const float4*)(Bw + (size_t)(k0 + bkr) * N + n0 + bcq);
        *(float4*)&Bs[bkr][bcq] = bv;
        __syncthreads();
#pragma unroll
        for (int kk = 0; kk < 16; ++kk) {
            float2 a2 = *(float2*)&As[kk][tr * 2];
            float4 b4 = *(float4*)&Bs[kk][tc * 4];
            acc[0][0] = fmaf(a2.x, b4.x, acc[0][0]);
            acc[0][1] = fmaf(a2.x, b4.y, acc[0][1]);
            acc[0][2] = fmaf(a2.x, b4.z, acc[0][2]);
            acc[0][3] = fmaf(a2.x, b4.w, acc[0][3]);
            acc[1][0] = fmaf(a2.y, b4.x, acc[1][0]);
            acc[1][1] = fmaf(a2.y, b4.y, acc[1][1]);
            acc[1][2] = fmaf(a2.y, b4.z, acc[1][2]);
            acc[1][3] = fmaf(a2.y, b4.w, acc[1][3]);
        }
        __syncthreads();
    }
    // epilogue: scatter to (B,H,T,E); tile lies in one qkv section
    int sec = n0 >> 8;
    float* dst = (sec == 0) ? qT : (sec == 1) ? kT : vT;
    int cc0 = (n0 & 255) + tc * 4;
    int h = cc0 >> 5;
    int e0 = cc0 & 31;
#pragma unroll
    for (int i = 0; i < 2; ++i) {
        int m = m0 + tr * 2 + i;
        int bq = m >> 9, t = m & (Tdim - 1);
        float4 val = make_float4(acc[i][0], acc[i][1], acc[i][2], acc[i][3]);
        *(float4*)&dst[(((size_t)bq * Hdim + h) * Tdim + t) * Edim + e0] = val;
    }
}

// ---------------------------------------------------------------------------
// Kernel 2: attention. grid = (32 tile-pairs, 16 bh), block = 512 (8 waves).
// Double-buffered kv tiles (1 barrier/tile), nibble-packed edge types staged
// once per rep (st1p[tile][j] holds 8 i-types), spartW overlaid on qm.
// LDS ~77.8 KB -> 2 blocks/CU.
// ---------------------------------------------------------------------------
__global__ __launch_bounds__(512, 4) void attn_kernel(
    const float* __restrict__ qT, const float* __restrict__ kT,
    const float* __restrict__ vT, const int* __restrict__ bm,
    const float* __restrict__ ekt, const float* __restrict__ evt,
    const float* __restrict__ abt, float* __restrict__ y)
{
    __shared__ float kv[2][JT][36];              // double-buffered k/v tile
    __shared__ float qm_spart[TI * NTYPES * 36]; // qm overlaid with spartW
    __shared__ float ss[TI][516];                // scores -> probs
    __shared__ unsigned int st1p[4][JT];         // nibble-packed types per tile
    __shared__ float sekt[NTYPES][36];
    __shared__ float sevt[NTYPES][36];
    __shared__ float sq[TI][36];
    __shared__ float sabt[NTYPES];
    __shared__ float sinv[TI];

    float (*qm)[NTYPES][36] = (float (*)[NTYPES][36])qm_spart;
    float (*spartW)[TI][Edim] = (float (*)[TI][Edim])qm_spart;

    const int pairIdx = blockIdx.x;   // 0..31
    const int bh = blockIdx.y;        // 0..15
    const int h = bh & (Hdim - 1);
    const int b = bh >> 3;
    const int tid = threadIdx.x;
    const int wave = tid >> 6;
    const int lane = tid & 63;
    const float inv_scale = 0.17677669529663687f;  // 1/sqrt(32)

    const float* qbase = qT + (size_t)bh * Tdim * Edim;
    const float* kbase = kT + (size_t)bh * Tdim * Edim;
    const float* vbase = vT + (size_t)bh * Tdim * Edim;
    const int* bmb = bm + (size_t)b * Tdim * Tdim;

    if (tid < 128) {
        int t = tid >> 3, eq = tid & 7;
        *(float4*)&sekt[t][eq * 4] = *(const float4*)&ekt[t * Cdim + h * Edim + eq * 4];
        *(float4*)&sevt[t][eq * 4] = *(const float4*)&evt[t * Cdim + h * Edim + eq * 4];
    }
    if (tid < NTYPES) sabt[tid] = abt[tid * Hdim + h];

    for (int rep = 0; rep < 2; ++rep) {
        int tau = rep ? (63 - pairIdx) : pairIdx;
        int i0 = tau * TI;
        int imax = i0 + TI - 1;
        int njt = (imax >> 7) + 1;

        __syncthreads();  // prev rep fully consumed / tables ready

        // stage q rows + k-tile 0 + st1p[0]
        if (tid < TI * 8) {
            int r = tid >> 3, eq = tid & 7;
            *(float4*)&sq[r][eq * 4] =
                *(const float4*)&qbase[(size_t)(i0 + r) * Edim + eq * 4];
        }
        {
            int r0 = tid >> 3, eq0 = tid & 7;
            *(float4*)&kv[0][r0][eq0 * 4] =
                *(const float4*)&kbase[(size_t)r0 * Edim + eq0 * 4];
            int idx1 = tid + 512;
            int r1 = idx1 >> 3, eq1 = idx1 & 7;
            *(float4*)&kv[0][r1][eq1 * 4] =
                *(const float4*)&kbase[(size_t)r1 * Edim + eq1 * 4];
        }
        if (tid < JT) {
            const int* rowp = bmb + (size_t)tid * Tdim + i0;
            int4 lo = *(const int4*)rowp;
            int4 hi = *(const int4*)(rowp + 4);
            st1p[0][tid] =
                ((unsigned)(lo.x & 15)) | (((unsigned)(lo.y & 15)) << 4) |
                (((unsigned)(lo.z & 15)) << 8) | (((unsigned)(lo.w & 15)) << 12) |
                (((unsigned)(hi.x & 15)) << 16) | (((unsigned)(hi.y & 15)) << 20) |
                (((unsigned)(hi.z & 15)) << 24) | (((unsigned)(hi.w & 15)) << 28);
        }
        __syncthreads();
        // build qm[ii][t][e] = q[i0+ii][e] * ekt[t][e]
        for (int idx = tid; idx < TI * NTYPES * 8; idx += 512) {
            int eq = idx & 7;
            int t = (idx >> 3) & (NTYPES - 1);
            int r = idx >> 7;
            float4 qv = *(float4*)&sq[r][eq * 4];
            float4 ev = *(float4*)&sekt[t][eq * 4];
            float4 o;
            o.x = qv.x * ev.x; o.y = qv.y * ev.y;
            o.z = qv.z * ev.z; o.w = qv.w * ev.w;
            *(float4*)&qm[r][t][eq * 4] = o;
        }
        __syncthreads();  // qm + tile 0 ready

        // ---------------- Pass A: scores (double-buffered) ----------------
        for (int jt = 0; jt < njt; ++jt) {
            int j0 = jt << 7;
            int nb = jt & 1;
            bool hn = (jt + 1 < njt);
            float4 pf0, pf1;
            unsigned pst = 0;
            if (hn) {
                int j0n = j0 + JT;
                int r0 = tid >> 3, eq0 = tid & 7;
                pf0 = *(const float4*)&kbase[(size_t)(j0n + r0) * Edim + eq0 * 4];
                int idx1 = tid + 512;
                int r1 = idx1 >> 3, eq1 = idx1 & 7;
                pf1 = *(const float4*)&kbase[(size_t)(j0n + r1) * Edim + eq1 * 4];
                if (tid < JT) {
                    const int* rowp = bmb + (size_t)(j0n + tid) * Tdim + i0;
                    int4 lo = *(const int4*)rowp;
                    int4 hi = *(const int4*)(rowp + 4);
                    pst =
                        ((unsigned)(lo.x & 15)) | (((unsigned)(lo.y & 15)) << 4) |
                        (((unsigned)(lo.z & 15)) << 8) | (((unsigned)(lo.w & 15)) << 12) |
                        (((unsigned)(hi.x & 15)) << 16) | (((unsigned)(hi.y & 15)) << 20) |
                        (((unsigned)(hi.z & 15)) << 24) | (((unsigned)(hi.w & 15)) << 28);
                }
            }
            // compute tile jt from kv[nb]
            int jsub = wave & 1;
            int jl = (jsub << 6) + lane;
            int j = j0 + jl;
            float4 k4[8];
#pragma unroll
            for (int eq = 0; eq < 8; ++eq) k4[eq] = *(float4*)&kv[nb][jl][eq * 4];
            unsigned tp = st1p[jt][jl];
#pragma unroll
            for (int u = 0; u < 2; ++u) {
                int ii = (wave >> 1) + (u << 2);
                int i = i0 + ii;
                if (j0 + (jsub << 6) > i) continue;   // wave-uniform skip
                int t1 = (tp >> (ii * 4)) & 15;
                int t2 = bmb[(size_t)i * Tdim + j];   // L2-resident
                float s = 0.f;
#pragma unroll
                for (int eq = 0; eq < 8; ++eq) {
                    float4 qv = *(float4*)&qm[ii][t1][eq * 4];
                    s = fmaf(qv.x, k4[eq].x, s);
                    s = fmaf(qv.y, k4[eq].y, s);
                    s = fmaf(qv.z, k4[eq].z, s);
                    s = fmaf(qv.w, k4[eq].w, s);
                }
                if (j <= i) ss[ii][j] = s * inv_scale + sabt[t2];
            }
            if (hn) {
                int ob = nb ^ 1;
                int r0 = tid >> 3, eq0 = tid & 7;
                *(float4*)&kv[ob][r0][eq0 * 4] = pf0;
                int idx1 = tid + 512;
                int r1 = idx1 >> 3, eq1 = idx1 & 7;
                *(float4*)&kv[ob][r1][eq1 * 4] = pf1;
                if (tid < JT) st1p[jt + 1][tid] = pst;
            }
            __syncthreads();
        }

        // stage v-tile 0 (overlaps softmax); all pass-A kv reads are done
        {
            int r0 = tid >> 3, eq0 = tid & 7;
            *(float4*)&kv[0][r0][eq0 * 4] =
                *(const float4*)&vbase[(size_t)r0 * Edim + eq0 * 4];
            int idx1 = tid + 512;
            int r1 = idx1 >> 3, eq1 = idx1 & 7;
            *(float4*)&kv[0][r1][eq1 * 4] =
                *(const float4*)&vbase[(size_t)r1 * Edim + eq1 * 4];
        }
        // ---------------- softmax (normalization deferred) ----------------
        {
            int ii = wave;
            int i = i0 + ii;
            float m = -1e30f;
            for (int j = lane; j <= i; j += 64) m = fmaxf(m, ss[ii][j]);
            for (int off = 32; off; off >>= 1) m = fmaxf(m, __shfl_xor(m, off));
            float sum = 0.f;
            for (int j = lane; j <= i; j += 64) {
                float p = __expf(ss[ii][j] - m);
                ss[ii][j] = p;
                sum += p;
            }
            for (int off = 32; off; off >>= 1) sum += __shfl_xor(sum, off);
            if (lane == 0) sinv[ii] = 1.0f / sum;
        }
        __syncthreads();

        // ---------------- Pass B: PV (double-buffered) ----------------
        float4 acc[TI];
#pragma unroll
        for (int ii = 0; ii < TI; ++ii) acc[ii] = make_float4(0.f, 0.f, 0.f, 0.f);
        int gid = tid >> 3;        // 64 groups of 8
        int eqg = tid & 7;
        for (int jt = 0; jt < njt; ++jt) {
            int j0 = jt << 7;
            int nb = jt & 1;
            bool hn = (jt + 1 < njt);
            float4 pf0, pf1;
            if (hn) {
                int j0n = j0 + JT;
                int r0 = tid >> 3, eq0 = tid & 7;
                pf0 = *(const float4*)&vbase[(size_t)(j0n + r0) * Edim + eq0 * 4];
                int idx1 = tid + 512;
                int r1 = idx1 >> 3, eq1 = idx1 & 7;
                pf1 = *(const float4*)&vbase[(size_t)(j0n + r1) * Edim + eq1 * 4];
            }
#pragma unroll
            for (int sub = 0; sub < 2; ++sub) {
                int jl = (sub << 6) + gid;
                int j = j0 + jl;
                float4 v4 = *(float4*)&kv[nb][jl][eqg * 4];
                unsigned tp = st1p[jt][jl];
#pragma unroll
                for (int ii = 0; ii < TI; ++ii) {
                    int i = i0 + ii;
                    if (j0 + (sub << 6) > i) continue;  // block-uniform skip
                    float p = (j <= i) ? ss[ii][j] : 0.f;
                    int t1 = (tp >> (ii * 4)) & 15;
                    float4 ev = *(float4*)&sevt[t1][eqg * 4];
                    acc[ii].x = fmaf(p * ev.x, v4.x, acc[ii].x);
                    acc[ii].y = fmaf(p * ev.y, v4.y, acc[ii].y);
                    acc[ii].z = fmaf(p * ev.z, v4.z, acc[ii].z);
                    acc[ii].w = fmaf(p * ev.w, v4.w, acc[ii].w);
                }
            }
            if (hn) {
                int ob = nb ^ 1;
                int r0 = tid >> 3, eq0 = tid & 7;
                *(float4*)&kv[ob][r0][eq0 * 4] = pf0;
                int idx1 = tid + 512;
                int r1 = idx1 >> 3, eq1 = idx1 & 7;
                *(float4*)&kv[ob][r1][eq1 * 4] = pf1;
            }
            __syncthreads();
        }
        // reduce across the wave's 8 groups (lane bits 3,4,5)
#pragma unroll
        for (int ii = 0; ii < TI; ++ii) {
#pragma unroll
            for (int m = 8; m <= 32; m <<= 1) {
                acc[ii].x += __shfl_xor(acc[ii].x, m);
                acc[ii].y += __shfl_xor(acc[ii].y, m);
                acc[ii].z += __shfl_xor(acc[ii].z, m);
                acc[ii].w += __shfl_xor(acc[ii].w, m);
            }
        }
        if (lane < 8) {
#pragma unroll
            for (int ii = 0; ii < TI; ++ii)
                *(float4*)&spartW[wave][ii][lane * 4] = acc[ii];
        }
        __syncthreads();
        if (tid < TI * Edim) {
            int ii = tid >> 5, e = tid & 31;
            float yv = 0.f;
#pragma unroll
            for (int w = 0; w < 8; ++w) yv += spartW[w][ii][e];
            yv *= sinv[ii];
            y[((size_t)(b * Tdim + i0 + ii)) * Cdim + h * Edim + e] = yv;
        }
    }
}

// ---------------------------------------------------------------------------
// Kernel 3: proj GEMM (M=1024, K=256, N=256) -> d_out (B,T,C), 32x64 tiles
// ---------------------------------------------------------------------------
__global__ __launch_bounds__(256) void proj_gemm_kernel(
    const float* __restrict__ A, const float* __restrict__ Bw,
    float* __restrict__ out)
{
    const int N = Cdim;
    const int K = Cdim;
    __shared__ float As[16][34];
    __shared__ float Bs[16][64];
    int m0 = blockIdx.y * 32;
    int n0 = blockIdx.x * 64;
    int tid = threadIdx.x;
    int tr = tid >> 4, tc = tid & 15;
    float acc[2][4] = {};
    int bkr = tid >> 4, bcq = (tid & 15) * 4;

    for (int k0 = 0; k0 < K; k0 += 16) {
        if (tid < 128) {
            int r = tid >> 2, kq = (tid & 3) * 4;
            float4 av = *(const float4*)(A + (size_t)(m0 + r) * K + k0 + kq);
            As[kq + 0][r] = av.x;
            As[kq + 1][r] = av.y;
            As[kq + 2][r] = av.z;
            As[kq + 3][r] = av.w;
        }
        float4 bv = *(const float4*)(Bw + (size_t)(k0 + bkr) * N + n0 + bcq);
        *(float4*)&Bs[bkr][bcq] = bv;
        __syncthreads();
#pragma unroll
        for (int kk = 0; kk < 16; ++kk) {
            float2 a2 = *(float2*)&As[kk][tr * 2];
            float4 b4 = *(float4*)&Bs[kk][tc * 4];
            acc[0][0] = fmaf(a2.x, b4.x, acc[0][0]);
            acc[0][1] = fmaf(a2.x, b4.y, acc[0][1]);
            acc[0][2] = fmaf(a2.x, b4.z, acc[0][2]);
            acc[0][3] = fmaf(a2.x, b4.w, acc[0][3]);
            acc[1][0] = fmaf(a2.y, b4.x, acc[1][0]);
            acc[1][1] = fmaf(a2.y, b4.y, acc[1][1]);
            acc[1][2] = fmaf(a2.y, b4.z, acc[1][2]);
            acc[1][3] = fmaf(a2.y, b4.w, acc[1][3]);
        }
        __syncthreads();
    }
#pragma unroll
    for (int i = 0; i < 2; ++i) {
        int m = m0 + tr * 2 + i;
        float4 val = make_float4(acc[i][0], acc[i][1], acc[i][2], acc[i][3]);
        *(float4*)&out[(size_t)m * N + n0 + tc * 4] = val;
    }
}

// ---------------------------------------------------------------------------
extern "C" void kernel_launch(void* const* d_in, const int* in_sizes, int n_in,
                              void* d_out, int out_size, void* d_ws, size_t ws_size,
                              hipStream_t stream) {
    (void)in_sizes; (void)n_in; (void)out_size; (void)ws_size;
    const float* x = (const float*)d_in[0];
    const int* bias_matrix = (const int*)d_in[1];
    const float* w_attn = (const float*)d_in[2];
    const float* w_proj = (const float*)d_in[3];
    const float* w_edge_k = (const float*)d_in[4];
    const float* w_edge_v = (const float*)d_in[5];
    const float* edge_emb = (const float*)d_in[6];
    const float* attn_bias = (const float*)d_in[7];
    float* out = (float*)d_out;

    const size_t n_qkv = (size_t)Bdim * Hdim * Tdim * Edim;
    float* ws = (float*)d_ws;
    float* qT = ws;
    float* kT = qT + n_qkv;
    float* vT = kT + n_qkv;
    float* y = vT + n_qkv;
    float* ekt = y + (size_t)Bdim * Tdim * Cdim;
    float* evt = ekt + (size_t)NTYPES * Cdim;

    pre_kernel<<<400, 256, 0, stream>>>(x, w_attn, edge_emb, w_edge_k, w_edge_v,
                                        qT, kT, vT, ekt, evt);
    attn_kernel<<<dim3(32, 16), 512, 0, stream>>>(qT, kT, vT, bias_matrix,
                                                  ekt, evt, attn_bias, y);
    proj_gemm_kernel<<<dim3(4, 32), 256, 0, stream>>>(y, w_proj, out);
}

// Round 5
// 133.640 us; speedup vs baseline: 1.0493x; 1.0493x over previous
//
#include <hip/hip_runtime.h>
#include <hip/hip_bf16.h>
#include <math.h>

// Problem constants
#define Bdim 2
#define Tdim 512
#define Cdim 256
#define Hdim 8
#define Edim 32
#define NTYPES 16
#define TI 8       // i-tile size
#define JT 128     // j-tile size

// ---------------------------------------------------------------------------
// Kernel 1: fused edge-tables + qkv GEMM.
// blocks 0..383: qkv GEMM (M=1024,K=256,N=768), 32x64 tile, scatter (B,H,T,E)
// blocks 384..399: ekt/evt = emb[t] @ w_edge_{k,v}
// ---------------------------------------------------------------------------
__global__ __launch_bounds__(256) void pre_kernel(
    const float* __restrict__ A, const float* __restrict__ Bw,
    const float* __restrict__ emb, const float* __restrict__ wk,
    const float* __restrict__ wv,
    float* __restrict__ qT, float* __restrict__ kT, float* __restrict__ vT,
    float* __restrict__ ekt, float* __restrict__ evt)
{
    __shared__ float smem[16 * 34 + 16 * 64];
    int tid = threadIdx.x;

    if (blockIdx.x >= 384) {
        // ---- edge tables ----
        int t = blockIdx.x - 384;
        float* se = smem;
        se[tid] = emb[t * Cdim + tid];
        __syncthreads();
        float a = 0.f, b = 0.f;
        for (int k = 0; k < Cdim; ++k) {
            float ev = se[k];
            a = fmaf(ev, wk[k * Cdim + tid], a);
            b = fmaf(ev, wv[k * Cdim + tid], b);
        }
        ekt[t * Cdim + tid] = a;
        evt[t * Cdim + tid] = b;
        return;
    }

    // ---- qkv GEMM, 32x64 tile, 256 threads, 2x4 per thread ----
    const int N = 3 * Cdim;
    const int K = Cdim;
    float (*As)[34] = (float(*)[34])smem;              // k-major
    float (*Bs)[64] = (float(*)[64])(smem + 16 * 34);
    int m0 = (blockIdx.x / 12) * 32;
    int n0 = (blockIdx.x % 12) * 64;
    int tr = tid >> 4, tc = tid & 15;
    float acc[2][4] = {};
    int bkr = tid >> 4, bcq = (tid & 15) * 4;

    for (int k0 = 0; k0 < K; k0 += 16) {
        if (tid < 128) {
            int r = tid >> 2, kq = (tid & 3) * 4;
            float4 av = *(const float4*)(A + (size_t)(m0 + r) * K + k0 + kq);
            As[kq + 0][r] = av.x;
            As[kq + 1][r] = av.y;
            As[kq + 2][r] = av.z;
            As[kq + 3][r] = av.w;
        }
        float4 bv = *(const float4*)(Bw + (size_t)(k0 + bkr) * N + n0 + bcq);
        *(float4*)&Bs[bkr][bcq] = bv;
        __syncthreads();
#pragma unroll
        for (int kk = 0; kk < 16; ++kk) {
            float2 a2 = *(float2*)&As[kk][tr * 2];
            float4 b4 = *(float4*)&Bs[kk][tc * 4];
            acc[0][0] = fmaf(a2.x, b4.x, acc[0][0]);
            acc[0][1] = fmaf(a2.x, b4.y, acc[0][1]);
            acc[0][2] = fmaf(a2.x, b4.z, acc[0][2]);
            acc[0][3] = fmaf(a2.x, b4.w, acc[0][3]);
            acc[1][0] = fmaf(a2.y, b4.x, acc[1][0]);
            acc[1][1] = fmaf(a2.y, b4.y, acc[1][1]);
            acc[1][2] = fmaf(a2.y, b4.z, acc[1][2]);
            acc[1][3] = fmaf(a2.y, b4.w, acc[1][3]);
        }
        __syncthreads();
    }
    int sec = n0 >> 8;
    float* dst = (sec == 0) ? qT : (sec == 1) ? kT : vT;
    int cc0 = (n0 & 255) + tc * 4;
    int h = cc0 >> 5;
    int e0 = cc0 & 31;
#pragma unroll
    for (int i = 0; i < 2; ++i) {
        int m = m0 + tr * 2 + i;
        int bq = m >> 9, t = m & (Tdim - 1);
        float4 val = make_float4(acc[i][0], acc[i][1], acc[i][2], acc[i][3]);
        *(float4*)&dst[(((size_t)bq * Hdim + h) * Tdim + t) * Edim + e0] = val;
    }
}

// ---------------------------------------------------------------------------
// Kernel 2: attention. grid = (32 tile-pairs, 16 bh), block = 512 (8 waves).
// R3 structure (single kv buffer, no register prefetch -> no spills) +
// nibble-packed edge types st1p[tile][j] staged ONCE per rep, shared by
// pass A and pass B. LDS ~69.5 KB -> 2 blocks/CU.
// ---------------------------------------------------------------------------
__global__ __launch_bounds__(512, 4) void attn_kernel(
    const float* __restrict__ qT, const float* __restrict__ kT,
    const float* __restrict__ vT, const int* __restrict__ bm,
    const float* __restrict__ ekt, const float* __restrict__ evt,
    const float* __restrict__ abt, float* __restrict__ y)
{
    __shared__ float kv[JT][36];                 // k or v tile
    __shared__ float qm[TI][NTYPES][36];         // q*ekt
    __shared__ float ss[TI][516];                // scores -> probs
    __shared__ unsigned int st1p[4][JT];         // nibble-packed types, whole rep
    __shared__ float sekt[NTYPES][36];
    __shared__ float sevt[NTYPES][36];
    __shared__ float sq[TI][36];
    __shared__ float sabt[NTYPES];
    __shared__ float sinv[TI];
    __shared__ float spartW[8][TI][Edim];

    const int pairIdx = blockIdx.x;   // 0..31
    const int bh = blockIdx.y;        // 0..15
    const int h = bh & (Hdim - 1);
    const int b = bh >> 3;
    const int tid = threadIdx.x;
    const int wave = tid >> 6;
    const int lane = tid & 63;
    const float inv_scale = 0.17677669529663687f;  // 1/sqrt(32)

    const float* qbase = qT + (size_t)bh * Tdim * Edim;
    const float* kbase = kT + (size_t)bh * Tdim * Edim;
    const float* vbase = vT + (size_t)bh * Tdim * Edim;
    const int* bmb = bm + (size_t)b * Tdim * Tdim;

    if (tid < 128) {
        int t = tid >> 3, eq = tid & 7;
        *(float4*)&sekt[t][eq * 4] = *(const float4*)&ekt[t * Cdim + h * Edim + eq * 4];
        *(float4*)&sevt[t][eq * 4] = *(const float4*)&evt[t * Cdim + h * Edim + eq * 4];
    }
    if (tid < NTYPES) sabt[tid] = abt[tid * Hdim + h];

    for (int rep = 0; rep < 2; ++rep) {
        int tau = rep ? (63 - pairIdx) : pairIdx;
        int i0 = tau * TI;
        int imax = i0 + TI - 1;
        int njt = (imax >> 7) + 1;

        __syncthreads();  // prev rep fully consumed / tables ready

        // stage q rows
        if (tid < TI * 8) {
            int r = tid >> 3, eq = tid & 7;
            *(float4*)&sq[r][eq * 4] =
                *(const float4*)&qbase[(size_t)(i0 + r) * Edim + eq * 4];
        }
        // stage ALL edge-type nibbles for this rep (tiles 0..njt-1)
        {
            int jt = tid >> 7, r = tid & 127;
            if (jt < njt) {
                const int* rowp = bmb + (size_t)(jt * JT + r) * Tdim + i0;
                int4 lo = *(const int4*)rowp;
                int4 hi = *(const int4*)(rowp + 4);
                st1p[jt][r] =
                    ((unsigned)(lo.x & 15)) | (((unsigned)(lo.y & 15)) << 4) |
                    (((unsigned)(lo.z & 15)) << 8) | (((unsigned)(lo.w & 15)) << 12) |
                    (((unsigned)(hi.x & 15)) << 16) | (((unsigned)(hi.y & 15)) << 20) |
                    (((unsigned)(hi.z & 15)) << 24) | (((unsigned)(hi.w & 15)) << 28);
            }
        }
        __syncthreads();
        // build qm[ii][t][e] = q[i0+ii][e] * ekt[t][e]
        for (int idx = tid; idx < TI * NTYPES * 8; idx += 512) {
            int eq = idx & 7;
            int t = (idx >> 3) & (NTYPES - 1);
            int r = idx >> 7;
            float4 qv = *(float4*)&sq[r][eq * 4];
            float4 ev = *(float4*)&sekt[t][eq * 4];
            float4 o;
            o.x = qv.x * ev.x; o.y = qv.y * ev.y;
            o.z = qv.z * ev.z; o.w = qv.w * ev.w;
            *(float4*)&qm[r][t][eq * 4] = o;
        }

        // ---------------- Pass A: scores ----------------
        for (int jt = 0; jt < njt; ++jt) {
            int j0 = jt << 7;
            __syncthreads();   // prev-tile consumers done (covers qm build jt=0)
            for (int idx = tid; idx < JT * 8; idx += 512) {
                int r = idx >> 3, eq = idx & 7;
                *(float4*)&kv[r][eq * 4] =
                    *(const float4*)&kbase[(size_t)(j0 + r) * Edim + eq * 4];
            }
            __syncthreads();

            int jsub = wave & 1;
            int jl = (jsub << 6) + lane;
            int j = j0 + jl;
            float4 k4[8];
#pragma unroll
            for (int eq = 0; eq < 8; ++eq) k4[eq] = *(float4*)&kv[jl][eq * 4];
            unsigned tp = st1p[jt][jl];

#pragma unroll
            for (int u = 0; u < 2; ++u) {
                int ii = (wave >> 1) + (u << 2);
                int i = i0 + ii;
                if (j0 + (jsub << 6) > i) continue;   // wave-uniform skip
                int t1 = (tp >> (ii * 4)) & 15;
                int t2 = bmb[(size_t)i * Tdim + j];   // L2-resident
                float s = 0.f;
#pragma unroll
                for (int eq = 0; eq < 8; ++eq) {
                    float4 qv = *(float4*)&qm[ii][t1][eq * 4];
                    s = fmaf(qv.x, k4[eq].x, s);
                    s = fmaf(qv.y, k4[eq].y, s);
                    s = fmaf(qv.z, k4[eq].z, s);
                    s = fmaf(qv.w, k4[eq].w, s);
                }
                if (j <= i) ss[ii][j] = s * inv_scale + sabt[t2];
            }
        }
        __syncthreads();

        // ---------------- softmax (normalization deferred) ----------------
        {
            int ii = wave;
            int i = i0 + ii;
            float m = -1e30f;
            for (int j = lane; j <= i; j += 64) m = fmaxf(m, ss[ii][j]);
            for (int off = 32; off; off >>= 1) m = fmaxf(m, __shfl_xor(m, off));
            float sum = 0.f;
            for (int j = lane; j <= i; j += 64) {
                float p = __expf(ss[ii][j] - m);
                ss[ii][j] = p;
                sum += p;
            }
            for (int off = 32; off; off >>= 1) sum += __shfl_xor(sum, off);
            if (lane == 0) sinv[ii] = 1.0f / sum;
        }

        // ---------------- Pass B: PV ----------------
        float4 acc[TI];
#pragma unroll
        for (int ii = 0; ii < TI; ++ii) acc[ii] = make_float4(0.f, 0.f, 0.f, 0.f);
        int gid = tid >> 3;        // 64 groups of 8
        int eqg = tid & 7;
        for (int jt = 0; jt < njt; ++jt) {
            int j0 = jt << 7;
            __syncthreads();   // softmax visible (jt=0) / prev-tile consumers done
            for (int idx = tid; idx < JT * 8; idx += 512) {
                int r = idx >> 3, eq = idx & 7;
                *(float4*)&kv[r][eq * 4] =
                    *(const float4*)&vbase[(size_t)(j0 + r) * Edim + eq * 4];
            }
            __syncthreads();
#pragma unroll
            for (int sub = 0; sub < 2; ++sub) {
                int jl = (sub << 6) + gid;
                int j = j0 + jl;
                float4 v4 = *(float4*)&kv[jl][eqg * 4];
                unsigned tp = st1p[jt][jl];
#pragma unroll
                for (int ii = 0; ii < TI; ++ii) {
                    int i = i0 + ii;
                    if (j0 + (sub << 6) > i) continue;  // block-uniform skip
                    float p = (j <= i) ? ss[ii][j] : 0.f;
                    int t1 = (tp >> (ii * 4)) & 15;
                    float4 ev = *(float4*)&sevt[t1][eqg * 4];
                    acc[ii].x = fmaf(p * ev.x, v4.x, acc[ii].x);
                    acc[ii].y = fmaf(p * ev.y, v4.y, acc[ii].y);
                    acc[ii].z = fmaf(p * ev.z, v4.z, acc[ii].z);
                    acc[ii].w = fmaf(p * ev.w, v4.w, acc[ii].w);
                }
            }
        }
        // reduce across the wave's 8 groups (lane bits 3,4,5)
#pragma unroll
        for (int ii = 0; ii < TI; ++ii) {
#pragma unroll
            for (int m = 8; m <= 32; m <<= 1) {
                acc[ii].x += __shfl_xor(acc[ii].x, m);
                acc[ii].y += __shfl_xor(acc[ii].y, m);
                acc[ii].z += __shfl_xor(acc[ii].z, m);
                acc[ii].w += __shfl_xor(acc[ii].w, m);
            }
        }
        __syncthreads();
        if (lane < 8) {
#pragma unroll
            for (int ii = 0; ii < TI; ++ii)
                *(float4*)&spartW[wave][ii][lane * 4] = acc[ii];
        }
        __syncthreads();
        if (tid < TI * Edim) {
            int ii = tid >> 5, e = tid & 31;
            float yv = 0.f;
#pragma unroll
            for (int w = 0; w < 8; ++w) yv += spartW[w][ii][e];
            yv *= sinv[ii];
            y[((size_t)(b * Tdim + i0 + ii)) * Cdim + h * Edim + e] = yv;
        }
    }
}

// ---------------------------------------------------------------------------
// Kernel 3: proj GEMM (M=1024, K=256, N=256) -> d_out (B,T,C), 32x64 tiles
// ---------------------------------------------------------------------------
__global__ __launch_bounds__(256) void proj_gemm_kernel(
    const float* __restrict__ A, const float* __restrict__ Bw,
    float* __restrict__ out)
{
    const int N = Cdim;
    const int K = Cdim;
    __shared__ float As[16][34];
    __shared__ float Bs[16][64];
    int m0 = blockIdx.y * 32;
    int n0 = blockIdx.x * 64;
    int tid = threadIdx.x;
    int tr = tid >> 4, tc = tid & 15;
    float acc[2][4] = {};
    int bkr = tid >> 4, bcq = (tid & 15) * 4;

    for (int k0 = 0; k0 < K; k0 += 16) {
        if (tid < 128) {
            int r = tid >> 2, kq = (tid & 3) * 4;
            float4 av = *(const float4*)(A + (size_t)(m0 + r) * K + k0 + kq);
            As[kq + 0][r] = av.x;
            As[kq + 1][r] = av.y;
            As[kq + 2][r] = av.z;
            As[kq + 3][r] = av.w;
        }
        float4 bv = *(const float4*)(Bw + (size_t)(k0 + bkr) * N + n0 + bcq);
        *(float4*)&Bs[bkr][bcq] = bv;
        __syncthreads();
#pragma unroll
        for (int kk = 0; kk < 16; ++kk) {
            float2 a2 = *(float2*)&As[kk][tr * 2];
            float4 b4 = *(float4*)&Bs[kk][tc * 4];
            acc[0][0] = fmaf(a2.x, b4.x, acc[0][0]);
            acc[0][1] = fmaf(a2.x, b4.y, acc[0][1]);
            acc[0][2] = fmaf(a2.x, b4.z, acc[0][2]);
            acc[0][3] = fmaf(a2.x, b4.w, acc[0][3]);
            acc[1][0] = fmaf(a2.y, b4.x, acc[1][0]);
            acc[1][1] = fmaf(a2.y, b4.y, acc[1][1]);
            acc[1][2] = fmaf(a2.y, b4.z, acc[1][2]);
            acc[1][3] = fmaf(a2.y, b4.w, acc[1][3]);
        }
        __syncthreads();
    }
#pragma unroll
    for (int i = 0; i < 2; ++i) {
        int m = m0 + tr * 2 + i;
        float4 val = make_float4(acc[i][0], acc[i][1], acc[i][2], acc[i][3]);
        *(float4*)&out[(size_t)m * N + n0 + tc * 4] = val;
    }
}

// ---------------------------------------------------------------------------
extern "C" void kernel_launch(void* const* d_in, const int* in_sizes, int n_in,
                              void* d_out, int out_size, void* d_ws, size_t ws_size,
                              hipStream_t stream) {
    (void)in_sizes; (void)n_in; (void)out_size; (void)ws_size;
    const float* x = (const float*)d_in[0];
    const int* bias_matrix = (const int*)d_in[1];
    const float* w_attn = (const float*)d_in[2];
    const float* w_proj = (const float*)d_in[3];
    const float* w_edge_k = (const float*)d_in[4];
    const float* w_edge_v = (const float*)d_in[5];
    const float* edge_emb = (const float*)d_in[6];
    const float* attn_bias = (const float*)d_in[7];
    float* out = (float*)d_out;

    const size_t n_qkv = (size_t)Bdim * Hdim * Tdim * Edim;
    float* ws = (float*)d_ws;
    float* qT = ws;
    float* kT = qT + n_qkv;
    float* vT = kT + n_qkv;
    float* y = vT + n_qkv;
    float* ekt = y + (size_t)Bdim * Tdim * Cdim;
    float* evt = ekt + (size_t)NTYPES * Cdim;

    pre_kernel<<<400, 256, 0, stream>>>(x, w_attn, edge_emb, w_edge_k, w_edge_v,
                                        qT, kT, vT, ekt, evt);
    attn_kernel<<<dim3(32, 16), 512, 0, stream>>>(qT, kT, vT, bias_matrix,
                                                  ekt, evt, attn_bias, y);
    proj_gemm_kernel<<<dim3(4, 32), 256, 0, stream>>>(y, w_proj, out);
}

// Round 6
// 133.043 us; speedup vs baseline: 1.0540x; 1.0045x over previous
//
#include <hip/hip_runtime.h>
#include <hip/hip_bf16.h>
#include <math.h>

// Problem constants
#define Bdim 2
#define Tdim 512
#define Cdim 256
#define Hdim 8
#define Edim 32
#define NTYPES 16
#define TI 8       // i-tile size
#define JT 128     // j-tile size

// ---------------------------------------------------------------------------
// Kernel 1: fused edge-tables + qkv GEMM.
// blocks 0..383: qkv GEMM (M=1024,K=256,N=768), 32x64 tile, scatter (B,H,T,E)
// blocks 384..399: ekt/evt = emb[t] @ w_edge_{k,v}
// ---------------------------------------------------------------------------
__global__ __launch_bounds__(256) void pre_kernel(
    const float* __restrict__ A, const float* __restrict__ Bw,
    const float* __restrict__ emb, const float* __restrict__ wk,
    const float* __restrict__ wv,
    float* __restrict__ qT, float* __restrict__ kT, float* __restrict__ vT,
    float* __restrict__ ekt, float* __restrict__ evt)
{
    __shared__ float smem[16 * 34 + 16 * 64];
    int tid = threadIdx.x;

    if (blockIdx.x >= 384) {
        // ---- edge tables ----
        int t = blockIdx.x - 384;
        float* se = smem;
        se[tid] = emb[t * Cdim + tid];
        __syncthreads();
        float a = 0.f, b = 0.f;
        for (int k = 0; k < Cdim; ++k) {
            float ev = se[k];
            a = fmaf(ev, wk[k * Cdim + tid], a);
            b = fmaf(ev, wv[k * Cdim + tid], b);
        }
        ekt[t * Cdim + tid] = a;
        evt[t * Cdim + tid] = b;
        return;
    }

    // ---- qkv GEMM, 32x64 tile, 256 threads, 2x4 per thread ----
    const int N = 3 * Cdim;
    const int K = Cdim;
    float (*As)[34] = (float(*)[34])smem;              // k-major
    float (*Bs)[64] = (float(*)[64])(smem + 16 * 34);
    int m0 = (blockIdx.x / 12) * 32;
    int n0 = (blockIdx.x % 12) * 64;
    int tr = tid >> 4, tc = tid & 15;
    float acc[2][4] = {};
    int bkr = tid >> 4, bcq = (tid & 15) * 4;

    for (int k0 = 0; k0 < K; k0 += 16) {
        if (tid < 128) {
            int r = tid >> 2, kq = (tid & 3) * 4;
            float4 av = *(const float4*)(A + (size_t)(m0 + r) * K + k0 + kq);
            As[kq + 0][r] = av.x;
            As[kq + 1][r] = av.y;
            As[kq + 2][r] = av.z;
            As[kq + 3][r] = av.w;
        }
        float4 bv = *(const float4*)(Bw + (size_t)(k0 + bkr) * N + n0 + bcq);
        *(float4*)&Bs[bkr][bcq] = bv;
        __syncthreads();
#pragma unroll
        for (int kk = 0; kk < 16; ++kk) {
            float2 a2 = *(float2*)&As[kk][tr * 2];
            float4 b4 = *(float4*)&Bs[kk][tc * 4];
            acc[0][0] = fmaf(a2.x, b4.x, acc[0][0]);
            acc[0][1] = fmaf(a2.x, b4.y, acc[0][1]);
            acc[0][2] = fmaf(a2.x, b4.z, acc[0][2]);
            acc[0][3] = fmaf(a2.x, b4.w, acc[0][3]);
            acc[1][0] = fmaf(a2.y, b4.x, acc[1][0]);
            acc[1][1] = fmaf(a2.y, b4.y, acc[1][1]);
            acc[1][2] = fmaf(a2.y, b4.z, acc[1][2]);
            acc[1][3] = fmaf(a2.y, b4.w, acc[1][3]);
        }
        __syncthreads();
    }
    int sec = n0 >> 8;
    float* dst = (sec == 0) ? qT : (sec == 1) ? kT : vT;
    int cc0 = (n0 & 255) + tc * 4;
    int h = cc0 >> 5;
    int e0 = cc0 & 31;
#pragma unroll
    for (int i = 0; i < 2; ++i) {
        int m = m0 + tr * 2 + i;
        int bq = m >> 9, t = m & (Tdim - 1);
        float4 val = make_float4(acc[i][0], acc[i][1], acc[i][2], acc[i][3]);
        *(float4*)&dst[(((size_t)bq * Hdim + h) * Tdim + t) * Edim + e0] = val;
    }
}

// ---------------------------------------------------------------------------
// Kernel 2: attention. grid = (32 tile-pairs, 16 bh), block = 512 (8 waves).
// R5 structure + (a) st2p nibble table kills all per-pair global t2 loads,
// (b) k0 prestaged during qm build, v0 prestaged during softmax,
// (c) spartW overlaid on qm (disjoint lifetimes). LDS ~62 KB -> 2 blocks/CU.
// NO register-held prefetch across compute (R4 spill lesson).
// ---------------------------------------------------------------------------
__global__ __launch_bounds__(512, 4) void attn_kernel(
    const float* __restrict__ qT, const float* __restrict__ kT,
    const float* __restrict__ vT, const int* __restrict__ bm,
    const float* __restrict__ ekt, const float* __restrict__ evt,
    const float* __restrict__ abt, float* __restrict__ y)
{
    __shared__ float kv[JT][36];                 // k or v tile
    __shared__ float qm[TI][NTYPES][36];         // q*ekt; later overlaid by spart
    __shared__ float ss[TI][516];                // scores -> probs
    __shared__ unsigned int st1pf[Tdim];         // nibbles of bm[b,j,i0+ii]
    __shared__ unsigned int st2pf[Tdim];         // nibbles of bm[b,i0+ii,j]
    __shared__ float sekt[NTYPES][36];
    __shared__ float sevt[NTYPES][36];
    __shared__ float sq[TI][36];
    __shared__ float sabt[NTYPES];
    __shared__ float sinv[TI];

    float* spart = (float*)qm;                   // overlay: [8][TI][Edim]

    const int pairIdx = blockIdx.x;   // 0..31
    const int bh = blockIdx.y;        // 0..15
    const int h = bh & (Hdim - 1);
    const int b = bh >> 3;
    const int tid = threadIdx.x;
    const int wave = tid >> 6;
    const int lane = tid & 63;
    const float inv_scale = 0.17677669529663687f;  // 1/sqrt(32)

    const float* qbase = qT + (size_t)bh * Tdim * Edim;
    const float* kbase = kT + (size_t)bh * Tdim * Edim;
    const float* vbase = vT + (size_t)bh * Tdim * Edim;
    const int* bmb = bm + (size_t)b * Tdim * Tdim;

    if (tid < 128) {
        int t = tid >> 3, eq = tid & 7;
        *(float4*)&sekt[t][eq * 4] = *(const float4*)&ekt[t * Cdim + h * Edim + eq * 4];
        *(float4*)&sevt[t][eq * 4] = *(const float4*)&evt[t * Cdim + h * Edim + eq * 4];
    }
    if (tid < NTYPES) sabt[tid] = abt[tid * Hdim + h];

    for (int rep = 0; rep < 2; ++rep) {
        int tau = rep ? (63 - pairIdx) : pairIdx;
        int i0 = tau * TI;
        int imax = i0 + TI - 1;
        int njt = (imax >> 7) + 1;
        int jmax = njt << 7;

        __syncthreads();  // prev rep fully consumed / tables ready

        // stage q rows
        if (tid < TI * 8) {
            int r = tid >> 3, eq = tid & 7;
            *(float4*)&sq[r][eq * 4] =
                *(const float4*)&qbase[(size_t)(i0 + r) * Edim + eq * 4];
        }
        // stage both nibble tables for the whole rep
        if (tid < jmax) {
            // st1pf[j]: bm[b, j, i0..i0+7]  (score/PV modulation types)
            const int* rowp = bmb + (size_t)tid * Tdim + i0;
            int4 lo = *(const int4*)rowp;
            int4 hi = *(const int4*)(rowp + 4);
            st1pf[tid] =
                ((unsigned)(lo.x & 15)) | (((unsigned)(lo.y & 15)) << 4) |
                (((unsigned)(lo.z & 15)) << 8) | (((unsigned)(lo.w & 15)) << 12) |
                (((unsigned)(hi.x & 15)) << 16) | (((unsigned)(hi.y & 15)) << 20) |
                (((unsigned)(hi.z & 15)) << 24) | (((unsigned)(hi.w & 15)) << 28);
            // st2pf[j]: bm[b, i0..i0+7, j]  (attn-bias types, transposed index)
            unsigned w2 = 0;
#pragma unroll
            for (int iiq = 0; iiq < 8; ++iiq)
                w2 |= ((unsigned)(bmb[(size_t)(i0 + iiq) * Tdim + tid] & 15)) << (iiq * 4);
            st2pf[tid] = w2;
        }
        // prestage k-tile 0 (overlaps with qm build below)
        {
            int r0 = tid >> 3, eq0 = tid & 7;
            *(float4*)&kv[r0][eq0 * 4] =
                *(const float4*)&kbase[(size_t)r0 * Edim + eq0 * 4];
            int idx1 = tid + 512;
            int r1 = idx1 >> 3, eq1 = idx1 & 7;
            *(float4*)&kv[r1][eq1 * 4] =
                *(const float4*)&kbase[(size_t)r1 * Edim + eq1 * 4];
        }
        __syncthreads();
        // build qm[ii][t][e] = q[i0+ii][e] * ekt[t][e]
        for (int idx = tid; idx < TI * NTYPES * 8; idx += 512) {
            int eq = idx & 7;
            int t = (idx >> 3) & (NTYPES - 1);
            int r = idx >> 7;
            float4 qv = *(float4*)&sq[r][eq * 4];
            float4 ev = *(float4*)&sekt[t][eq * 4];
            float4 o;
            o.x = qv.x * ev.x; o.y = qv.y * ev.y;
            o.z = qv.z * ev.z; o.w = qv.w * ev.w;
            *(float4*)&qm[r][t][eq * 4] = o;
        }

        // ---------------- Pass A: scores ----------------
        for (int jt = 0; jt < njt; ++jt) {
            int j0 = jt << 7;
            if (jt > 0) {
                __syncthreads();   // prev tile consumed
                for (int idx = tid; idx < JT * 8; idx += 512) {
                    int r = idx >> 3, eq = idx & 7;
                    *(float4*)&kv[r][eq * 4] =
                        *(const float4*)&kbase[(size_t)(j0 + r) * Edim + eq * 4];
                }
            }
            __syncthreads();       // jt=0: qm+k0 ready; jt>0: staged

            int jsub = wave & 1;
            int jl = (jsub << 6) + lane;
            int j = j0 + jl;
            float4 k4[8];
#pragma unroll
            for (int eq = 0; eq < 8; ++eq) k4[eq] = *(float4*)&kv[jl][eq * 4];
            unsigned tp = st1pf[j];
            unsigned tp2 = st2pf[j];

#pragma unroll
            for (int u = 0; u < 2; ++u) {
                int ii = (wave >> 1) + (u << 2);
                int i = i0 + ii;
                if (j0 + (jsub << 6) > i) continue;   // wave-uniform skip
                int t1 = (tp >> (ii * 4)) & 15;
                int t2 = (tp2 >> (ii * 4)) & 15;
                float s = 0.f;
#pragma unroll
                for (int eq = 0; eq < 8; ++eq) {
                    float4 qv = *(float4*)&qm[ii][t1][eq * 4];
                    s = fmaf(qv.x, k4[eq].x, s);
                    s = fmaf(qv.y, k4[eq].y, s);
                    s = fmaf(qv.z, k4[eq].z, s);
                    s = fmaf(qv.w, k4[eq].w, s);
                }
                if (j <= i) ss[ii][j] = s * inv_scale + sabt[t2];
            }
        }
        __syncthreads();   // all scores written; all pass-A kv reads done

        // prestage v-tile 0 (overlaps softmax)
        {
            int r0 = tid >> 3, eq0 = tid & 7;
            *(float4*)&kv[r0][eq0 * 4] =
                *(const float4*)&vbase[(size_t)r0 * Edim + eq0 * 4];
            int idx1 = tid + 512;
            int r1 = idx1 >> 3, eq1 = idx1 & 7;
            *(float4*)&kv[r1][eq1 * 4] =
                *(const float4*)&vbase[(size_t)r1 * Edim + eq1 * 4];
        }
        // ---------------- softmax (normalization deferred) ----------------
        {
            int ii = wave;
            int i = i0 + ii;
            float m = -1e30f;
            for (int j = lane; j <= i; j += 64) m = fmaxf(m, ss[ii][j]);
            for (int off = 32; off; off >>= 1) m = fmaxf(m, __shfl_xor(m, off));
            float sum = 0.f;
            for (int j = lane; j <= i; j += 64) {
                float p = __expf(ss[ii][j] - m);
                ss[ii][j] = p;
                sum += p;
            }
            for (int off = 32; off; off >>= 1) sum += __shfl_xor(sum, off);
            if (lane == 0) sinv[ii] = 1.0f / sum;
        }

        // ---------------- Pass B: PV ----------------
        float4 acc[TI];
#pragma unroll
        for (int ii = 0; ii < TI; ++ii) acc[ii] = make_float4(0.f, 0.f, 0.f, 0.f);
        int gid = tid >> 3;        // 64 groups of 8
        int eqg = tid & 7;
        for (int jt = 0; jt < njt; ++jt) {
            int j0 = jt << 7;
            if (jt > 0) {
                __syncthreads();   // prev v-tile consumed
                for (int idx = tid; idx < JT * 8; idx += 512) {
                    int r = idx >> 3, eq = idx & 7;
                    *(float4*)&kv[r][eq * 4] =
                        *(const float4*)&vbase[(size_t)(j0 + r) * Edim + eq * 4];
                }
            }
            __syncthreads();       // jt=0: v0 + softmax visible; jt>0: staged
#pragma unroll
            for (int sub = 0; sub < 2; ++sub) {
                int jl = (sub << 6) + gid;
                int j = j0 + jl;
                float4 v4 = *(float4*)&kv[jl][eqg * 4];
                unsigned tp = st1pf[j];
#pragma unroll
                for (int ii = 0; ii < TI; ++ii) {
                    int i = i0 + ii;
                    if (j0 + (sub << 6) > i) continue;  // block-uniform skip
                    float p = (j <= i) ? ss[ii][j] : 0.f;
                    int t1 = (tp >> (ii * 4)) & 15;
                    float4 ev = *(float4*)&sevt[t1][eqg * 4];
                    acc[ii].x = fmaf(p * ev.x, v4.x, acc[ii].x);
                    acc[ii].y = fmaf(p * ev.y, v4.y, acc[ii].y);
                    acc[ii].z = fmaf(p * ev.z, v4.z, acc[ii].z);
                    acc[ii].w = fmaf(p * ev.w, v4.w, acc[ii].w);
                }
            }
        }
        // reduce across the wave's 8 groups (lane bits 3,4,5)
#pragma unroll
        for (int ii = 0; ii < TI; ++ii) {
#pragma unroll
            for (int m = 8; m <= 32; m <<= 1) {
                acc[ii].x += __shfl_xor(acc[ii].x, m);
                acc[ii].y += __shfl_xor(acc[ii].y, m);
                acc[ii].z += __shfl_xor(acc[ii].z, m);
                acc[ii].w += __shfl_xor(acc[ii].w, m);
            }
        }
        // spart overlays qm: all qm reads ended before pass A's final barrier,
        // which every wave has passed (pass-B barriers). Safe to write.
        if (lane < 8) {
#pragma unroll
            for (int ii = 0; ii < TI; ++ii)
                *(float4*)&spart[((wave * TI + ii) << 5) + lane * 4] = acc[ii];
        }
        __syncthreads();
        if (tid < TI * Edim) {
            int ii = tid >> 5, e = tid & 31;
            float yv = 0.f;
#pragma unroll
            for (int w = 0; w < 8; ++w) yv += spart[((w * TI + ii) << 5) + e];
            yv *= sinv[ii];
            y[((size_t)(b * Tdim + i0 + ii)) * Cdim + h * Edim + e] = yv;
        }
    }
}

// ---------------------------------------------------------------------------
// Kernel 3: proj GEMM (M=1024, K=256, N=256) -> d_out (B,T,C), 32x64 tiles
// ---------------------------------------------------------------------------
__global__ __launch_bounds__(256) void proj_gemm_kernel(
    const float* __restrict__ A, const float* __restrict__ Bw,
    float* __restrict__ out)
{
    const int N = Cdim;
    const int K = Cdim;
    __shared__ float As[16][34];
    __shared__ float Bs[16][64];
    int m0 = blockIdx.y * 32;
    int n0 = blockIdx.x * 64;
    int tid = threadIdx.x;
    int tr = tid >> 4, tc = tid & 15;
    float acc[2][4] = {};
    int bkr = tid >> 4, bcq = (tid & 15) * 4;

    for (int k0 = 0; k0 < K; k0 += 16) {
        if (tid < 128) {
            int r = tid >> 2, kq = (tid & 3) * 4;
            float4 av = *(const float4*)(A + (size_t)(m0 + r) * K + k0 + kq);
            As[kq + 0][r] = av.x;
            As[kq + 1][r] = av.y;
            As[kq + 2][r] = av.z;
            As[kq + 3][r] = av.w;
        }
        float4 bv = *(const float4*)(Bw + (size_t)(k0 + bkr) * N + n0 + bcq);
        *(float4*)&Bs[bkr][bcq] = bv;
        __syncthreads();
#pragma unroll
        for (int kk = 0; kk < 16; ++kk) {
            float2 a2 = *(float2*)&As[kk][tr * 2];
            float4 b4 = *(float4*)&Bs[kk][tc * 4];
            acc[0][0] = fmaf(a2.x, b4.x, acc[0][0]);
            acc[0][1] = fmaf(a2.x, b4.y, acc[0][1]);
            acc[0][2] = fmaf(a2.x, b4.z, acc[0][2]);
            acc[0][3] = fmaf(a2.x, b4.w, acc[0][3]);
            acc[1][0] = fmaf(a2.y, b4.x, acc[1][0]);
            acc[1][1] = fmaf(a2.y, b4.y, acc[1][1]);
            acc[1][2] = fmaf(a2.y, b4.z, acc[1][2]);
            acc[1][3] = fmaf(a2.y, b4.w, acc[1][3]);
        }
        __syncthreads();
    }
#pragma unroll
    for (int i = 0; i < 2; ++i) {
        int m = m0 + tr * 2 + i;
        float4 val = make_float4(acc[i][0], acc[i][1], acc[i][2], acc[i][3]);
        *(float4*)&out[(size_t)m * N + n0 + tc * 4] = val;
    }
}

// ---------------------------------------------------------------------------
extern "C" void kernel_launch(void* const* d_in, const int* in_sizes, int n_in,
                              void* d_out, int out_size, void* d_ws, size_t ws_size,
                              hipStream_t stream) {
    (void)in_sizes; (void)n_in; (void)out_size; (void)ws_size;
    const float* x = (const float*)d_in[0];
    const int* bias_matrix = (const int*)d_in[1];
    const float* w_attn = (const float*)d_in[2];
    const float* w_proj = (const float*)d_in[3];
    const float* w_edge_k = (const float*)d_in[4];
    const float* w_edge_v = (const float*)d_in[5];
    const float* edge_emb = (const float*)d_in[6];
    const float* attn_bias = (const float*)d_in[7];
    float* out = (float*)d_out;

    const size_t n_qkv = (size_t)Bdim * Hdim * Tdim * Edim;
    float* ws = (float*)d_ws;
    float* qT = ws;
    float* kT = qT + n_qkv;
    float* vT = kT + n_qkv;
    float* y = vT + n_qkv;
    float* ekt = y + (size_t)Bdim * Tdim * Cdim;
    float* evt = ekt + (size_t)NTYPES * Cdim;

    pre_kernel<<<400, 256, 0, stream>>>(x, w_attn, edge_emb, w_edge_k, w_edge_v,
                                        qT, kT, vT, ekt, evt);
    attn_kernel<<<dim3(32, 16), 512, 0, stream>>>(qT, kT, vT, bias_matrix,
                                                  ekt, evt, attn_bias, y);
    proj_gemm_kernel<<<dim3(4, 32), 256, 0, stream>>>(y, w_proj, out);
}